// Round 10
// baseline (243.917 us; speedup 1.0000x reference)
//
#include <hip/hip_runtime.h>

static constexpr int IN_C  = 128;
static constexpr int HID   = 96;
static constexpr int OUT_C = 48;

static constexpr int NPART     = 8;     // XCD count on MI355X (perf heuristic only)
static constexpr int FILL_ITER = 16;
static constexpr int CHUNK     = 256 * FILL_ITER;  // edges per chunk

// ---------------- CSR build ----------------

// count in-degree AND record each edge's slot within its dst segment
__global__ void k_count(const int* __restrict__ dst, int* __restrict__ cnt,
                        int* __restrict__ perm, int E) {
  int e = blockIdx.x * blockDim.x + threadIdx.x;
  if (e < E) perm[e] = atomicAdd(&cnt[dst[e]], 1);
}

// exclusive block scan (256/block), emits per-block total
__global__ void k_scan_block(const int* __restrict__ in, int* __restrict__ out_excl,
                             int* __restrict__ bsum, int n) {
  __shared__ int sm[256];
  int i = blockIdx.x * 256 + threadIdx.x;
  int v = (i < n) ? in[i] : 0;
  int val = v;
  sm[threadIdx.x] = val;
  __syncthreads();
  for (int off = 1; off < 256; off <<= 1) {
    int t = (threadIdx.x >= (unsigned)off) ? sm[threadIdx.x - off] : 0;
    __syncthreads();
    val += t;
    sm[threadIdx.x] = val;
    __syncthreads();
  }
  if (i < n) out_excl[i] = val - v;
  if (threadIdx.x == 255) bsum[blockIdx.x] = val;
}

__global__ void k_finish(int* __restrict__ rs, const int* __restrict__ boff,
                         const int* __restrict__ cnt,
                         float* __restrict__ dinv, int n) {
  int i = blockIdx.x * 256 + threadIdx.x;
  if (i >= n) return;
  rs[i] = rs[i] + boff[blockIdx.x];
  dinv[i] = rsqrtf((float)cnt[i] + 1.0f);   // deg includes self-loop, always >= 1
}

// Partitioned fill: workgroup (x, y) scans edge-chunk y, writes only edges with
// dst in partition x -> each partition's csr writes land in a contiguous slice,
// merging fully in one XCD's L2 (bid = x + 8*y, round-robin XCD placement).
__global__ __launch_bounds__(256) void k_fill_part(
    const int* __restrict__ src, const int* __restrict__ dst,
    const int* __restrict__ perm, const int* __restrict__ rs,
    int* __restrict__ csr, int E, int P) {
  int lo = blockIdx.x * P;
  int hi = lo + P;
  int base = blockIdx.y * CHUNK + threadIdx.x;
#pragma unroll
  for (int i = 0; i < FILL_ITER; ++i) {
    int e = base + i * 256;
    if (e < E) {
      int d = dst[e];
      if (d >= lo && d < hi) {
        csr[rs[d] + perm[e]] = src[e];
      }
    }
  }
}

// ---------------- GEMM: Y[N x M] = dinv[r] * (X[N x K] @ W[K x M]) ----------------
// Wave-uniform weight panels: each wave owns 64 rows (lane = row) x 4 cols.
// jc is readfirstlane'd -> W loads are uniform-address -> scalar (s_load) pipe,
// leaving VMEM for the single X float4 per k-chunk. 16 FMA per VMEM instr.
// Grid: (ceil(N/64), M/16), block = 256 (4 waves = 4 col-groups).

__device__ __forceinline__ void fma4(float4& a, float s, const float4& w) {
  a.x = fmaf(s, w.x, a.x); a.y = fmaf(s, w.y, a.y);
  a.z = fmaf(s, w.z, a.z); a.w = fmaf(s, w.w, a.w);
}

template <int K, int M>
__global__ __launch_bounds__(256) void k_gemm(const float* __restrict__ X,
                                              const float* __restrict__ W,
                                              const float* __restrict__ dinv,
                                              float* __restrict__ Y, int N) {
  int lane = threadIdx.x & 63;
  int wv   = threadIdx.x >> 6;                   // 0..3
  int row  = blockIdx.x * 64 + lane;
  int jc   = __builtin_amdgcn_readfirstlane(blockIdx.y * 16 + wv * 4);
  const float* Wp = W + jc;                      // uniform across wave
  int rowc = min(row, N - 1);                    // clamp; store is guarded
  const float* xr = X + (size_t)rowc * K;
  float4 acc = {0.f, 0.f, 0.f, 0.f};
#pragma unroll 4
  for (int k = 0; k < K; k += 4) {
    float4 xv = *(const float4*)(xr + k);
    float4 w0 = *(const float4*)(Wp + (size_t)(k + 0) * M);
    float4 w1 = *(const float4*)(Wp + (size_t)(k + 1) * M);
    float4 w2 = *(const float4*)(Wp + (size_t)(k + 2) * M);
    float4 w3 = *(const float4*)(Wp + (size_t)(k + 3) * M);
    fma4(acc, xv.x, w0);
    fma4(acc, xv.y, w1);
    fma4(acc, xv.z, w2);
    fma4(acc, xv.w, w3);
  }
  if (row < N) {
    float d = dinv[row];
    *(float4*)(Y + (size_t)row * M + jc) =
        make_float4(acc.x * d, acc.y * d, acc.z * d, acc.w * d);
  }
}

// ---------------- Aggregation ----------------
// Hs is pre-scaled by dinv (in GEMM epilogue).
// out[n,f4] = dinv[n] * (Hs[n,f4] + sum_s Hs[s,f4]) + b[f4]; optional relu.

template <int M, bool RELU>
__global__ __launch_bounds__(256) void k_agg(const float* __restrict__ Hs,
                                             const int* __restrict__ csr,
                                             const int* __restrict__ rs,
                                             const int* __restrict__ cnt,
                                             const float* __restrict__ dinv,
                                             const float* __restrict__ bias,
                                             float* __restrict__ out, int N) {
  constexpr int JC = M / 4;
  int gid = blockIdx.x * blockDim.x + threadIdx.x;
  int n = gid / JC;
  if (n >= N) return;
  int f4 = (gid - n * JC) * 4;
  float dn = dinv[n];
  float4 acc = *(const float4*)(Hs + (size_t)n * M + f4);   // self-loop term
  int p = rs[n];
  int e = cnt[n];
  int i = 0;
  for (; i + 4 <= e; i += 4) {
    int s0 = csr[p + i];
    int s1 = csr[p + i + 1];
    int s2 = csr[p + i + 2];
    int s3 = csr[p + i + 3];
    float4 h0 = *(const float4*)(Hs + (size_t)s0 * M + f4);
    float4 h1 = *(const float4*)(Hs + (size_t)s1 * M + f4);
    float4 h2 = *(const float4*)(Hs + (size_t)s2 * M + f4);
    float4 h3 = *(const float4*)(Hs + (size_t)s3 * M + f4);
    acc.x += (h0.x + h1.x) + (h2.x + h3.x);
    acc.y += (h0.y + h1.y) + (h2.y + h3.y);
    acc.z += (h0.z + h1.z) + (h2.z + h3.z);
    acc.w += (h0.w + h1.w) + (h2.w + h3.w);
  }
  for (; i < e; ++i) {
    int s = csr[p + i];
    float4 h = *(const float4*)(Hs + (size_t)s * M + f4);
    acc.x += h.x; acc.y += h.y; acc.z += h.z; acc.w += h.w;
  }
  float4 b = *(const float4*)(bias + f4);
  float4 r;
  r.x = fmaf(dn, acc.x, b.x);
  r.y = fmaf(dn, acc.y, b.y);
  r.z = fmaf(dn, acc.z, b.z);
  r.w = fmaf(dn, acc.w, b.w);
  if (RELU) {
    r.x = fmaxf(r.x, 0.0f); r.y = fmaxf(r.y, 0.0f);
    r.z = fmaxf(r.z, 0.0f); r.w = fmaxf(r.w, 0.0f);
  }
  *(float4*)(out + (size_t)n * M + f4) = r;
}

// ---------------- launch ----------------

extern "C" void kernel_launch(void* const* d_in, const int* in_sizes, int n_in,
                              void* d_out, int out_size, void* d_ws, size_t ws_size,
                              hipStream_t stream) {
  const float* x  = (const float*)d_in[0];
  const int*   ei = (const int*)d_in[1];
  const float* W1 = (const float*)d_in[2];
  const float* b1 = (const float*)d_in[3];
  const float* W2 = (const float*)d_in[4];
  const float* b2 = (const float*)d_in[5];
  float* out = (float*)d_out;

  const int N = in_sizes[0] / IN_C;     // 50000
  const int E = in_sizes[1] / 2;        // 800000
  const int* src = ei;
  const int* dst = ei + E;

  char* ws = (char*)d_ws;
  size_t off = 0;
  auto alloc = [&](size_t bytes) -> void* {
    void* p = ws + off;
    off = (off + bytes + 255) & ~(size_t)255;
    return p;
  };
  int*   cnt    = (int*)alloc((size_t)N * 4);
  int*   rs     = (int*)alloc((size_t)N * 4);
  float* dinv   = (float*)alloc((size_t)N * 4);
  int*   bsum   = (int*)alloc(256 * 4);
  int*   boff   = (int*)alloc(256 * 4);
  int*   junk   = (int*)alloc(256 * 4);
  int*   perm   = (int*)alloc((size_t)E * 4);
  int*   csr    = (int*)alloc((size_t)E * 4);
  float* h1     = (float*)alloc((size_t)N * HID * 4);   // reused as h2 later
  float* h      = (float*)alloc((size_t)N * HID * 4);

  const int nbN = (N + 255) / 256;
  const int nbE = (E + 255) / 256;
  const int P   = (N + NPART - 1) / NPART;

  hipMemsetAsync(cnt, 0, (size_t)N * 4, stream);
  k_count<<<nbE, 256, 0, stream>>>(dst, cnt, perm, E);
  k_scan_block<<<nbN, 256, 0, stream>>>(cnt, rs, bsum, N);
  k_scan_block<<<1, 256, 0, stream>>>(bsum, boff, junk, nbN);
  k_finish<<<nbN, 256, 0, stream>>>(rs, boff, cnt, dinv, N);
  dim3 fg(NPART, (E + CHUNK - 1) / CHUNK);
  k_fill_part<<<fg, 256, 0, stream>>>(src, dst, perm, rs, csr, E, P);

  const int rowBlocks = (N + 63) / 64;

  // layer 1: h1 = dinv * (x @ W1) ; h = relu(dinv*(agg(h1)) + b1)
  {
    dim3 g1(rowBlocks, HID / 16);
    k_gemm<IN_C, HID><<<g1, 256, 0, stream>>>(x, W1, dinv, h1, N);
    int t2 = N * (HID / 4);
    k_agg<HID, true><<<(t2 + 255) / 256, 256, 0, stream>>>(h1, csr, rs, cnt, dinv, b1, h, N);
  }
  // layer 2: h2 = dinv * (h @ W2) (into h1 buffer) ; out = dinv*agg(h2) + b2
  {
    dim3 g2(rowBlocks, OUT_C / 16);
    k_gemm<HID, OUT_C><<<g2, 256, 0, stream>>>(h, W2, dinv, h1, N);
    int t2 = N * (OUT_C / 4);
    k_agg<OUT_C, false><<<(t2 + 255) / 256, 256, 0, stream>>>(h1, csr, rs, cnt, dinv, b2, out, N);
  }
}

// Round 11
// 192.767 us; speedup vs baseline: 1.2653x; 1.2653x over previous
//
#include <hip/hip_runtime.h>

static constexpr int IN_C  = 128;
static constexpr int HID   = 96;
static constexpr int OUT_C = 48;

static constexpr int NPART     = 8;     // XCD count on MI355X (perf heuristic only)
static constexpr int FILL_ITER = 16;
static constexpr int CHUNK     = 256 * FILL_ITER;  // edges per chunk

// ---------------- CSR build ----------------

// count in-degree AND record each edge's slot within its dst segment
__global__ void k_count(const int* __restrict__ dst, int* __restrict__ cnt,
                        int* __restrict__ perm, int E) {
  int e = blockIdx.x * blockDim.x + threadIdx.x;
  if (e < E) perm[e] = atomicAdd(&cnt[dst[e]], 1);
}

// exclusive block scan (256/block), emits per-block total
__global__ void k_scan_block(const int* __restrict__ in, int* __restrict__ out_excl,
                             int* __restrict__ bsum, int n) {
  __shared__ int sm[256];
  int i = blockIdx.x * 256 + threadIdx.x;
  int v = (i < n) ? in[i] : 0;
  int val = v;
  sm[threadIdx.x] = val;
  __syncthreads();
  for (int off = 1; off < 256; off <<= 1) {
    int t = (threadIdx.x >= (unsigned)off) ? sm[threadIdx.x - off] : 0;
    __syncthreads();
    val += t;
    sm[threadIdx.x] = val;
    __syncthreads();
  }
  if (i < n) out_excl[i] = val - v;
  if (threadIdx.x == 255) bsum[blockIdx.x] = val;
}

__global__ void k_finish(int* __restrict__ rs, const int* __restrict__ boff,
                         const int* __restrict__ cnt,
                         float* __restrict__ dinv, int n) {
  int i = blockIdx.x * 256 + threadIdx.x;
  if (i >= n) return;
  rs[i] = rs[i] + boff[blockIdx.x];
  dinv[i] = rsqrtf((float)cnt[i] + 1.0f);   // deg includes self-loop, always >= 1
}

// Partitioned fill: workgroup (x, y) scans edge-chunk y, writes only edges with
// dst in partition x -> each partition's csr writes land in a contiguous slice,
// merging fully in one XCD's L2 (bid = x + 8*y, round-robin XCD placement).
__global__ __launch_bounds__(256) void k_fill_part(
    const int* __restrict__ src, const int* __restrict__ dst,
    const int* __restrict__ perm, const int* __restrict__ rs,
    int* __restrict__ csr, int E, int P) {
  int lo = blockIdx.x * P;
  int hi = lo + P;
  int base = blockIdx.y * CHUNK + threadIdx.x;
#pragma unroll
  for (int i = 0; i < FILL_ITER; ++i) {
    int e = base + i * 256;
    if (e < E) {
      int d = dst[e];
      if (d >= lo && d < hi) {
        csr[rs[d] + perm[e]] = src[e];
      }
    }
  }
}

// ---------------- GEMM: Y[N x M] = dinv[r] * (X[N x K] @ W[K x M]) ----------------
// LDS-staged: block of 384 threads stages a 64-row X tile (full K) into LDS with
// coalesced float4 loads, then computes from LDS. Row stride K+4 floats:
// 16B-aligned and (K+4)%32==4 -> ds_read_b128 rows spread across banks
// (<=2-way aliasing, free). Thread tile: R rows x 4 cols; per 4-k chunk:
// R ds_read_b128 + 4 W float4 (contiguous across jc lanes) + 16R FMA.
// X touches HBM exactly once. Occupancy: LDS 33.8KB -> 4 blocks/CU (75%).

__device__ __forceinline__ void fma4(float4& a, float s, const float4& w) {
  a.x = fmaf(s, w.x, a.x); a.y = fmaf(s, w.y, a.y);
  a.z = fmaf(s, w.z, a.z); a.w = fmaf(s, w.w, a.w);
}

template <int K, int M, int JC, int R>
__global__ __launch_bounds__(384) void k_gemm(const float* __restrict__ X,
                                              const float* __restrict__ W,
                                              const float* __restrict__ dinv,
                                              float* __restrict__ Y, int N) {
  static_assert(384 % JC == 0 && (384 / JC) * R == 64, "tile mapping");
  constexpr int STRIDE = K + 4;           // floats: 16B-aligned, %32==4
  __shared__ float lds[64 * STRIDE];
  const int tid  = threadIdx.x;
  const int base = blockIdx.x * 64;

  // ---- stage 64 rows x K cols, coalesced float4 ----
  constexpr int KC = K / 4;               // float4s per row
  constexpr int NF4 = 64 * KC;
  for (int idx = tid; idx < NF4; idx += 384) {
    int row = idx / KC;
    int kc  = idx - row * KC;
    int srow = min(base + row, N - 1);    // clamp (store guarded later)
    float4 v = *(const float4*)(X + (size_t)srow * K + kc * 4);
    *(float4*)(&lds[row * STRIDE + kc * 4]) = v;
  }
  __syncthreads();

  const int jc = (tid % JC) * 4;
  const int rg = tid / JC;
  float4 acc[R] = {};

#pragma unroll 2
  for (int k = 0; k < K; k += 4) {
    const float* wk = W + (size_t)k * M + jc;
    float4 w0 = *(const float4*)(wk);
    float4 w1 = *(const float4*)(wk + M);
    float4 w2 = *(const float4*)(wk + 2 * M);
    float4 w3 = *(const float4*)(wk + 3 * M);
#pragma unroll
    for (int i = 0; i < R; ++i) {
      float4 xv = *(const float4*)(&lds[(rg * R + i) * STRIDE + k]);
      fma4(acc[i], xv.x, w0);
      fma4(acc[i], xv.y, w1);
      fma4(acc[i], xv.z, w2);
      fma4(acc[i], xv.w, w3);
    }
  }

#pragma unroll
  for (int i = 0; i < R; ++i) {
    int row = base + rg * R + i;
    if (row < N) {
      float d = dinv[row];
      *(float4*)(Y + (size_t)row * M + jc) =
          make_float4(acc[i].x * d, acc[i].y * d, acc[i].z * d, acc[i].w * d);
    }
  }
}

// ---------------- Aggregation ----------------
// Hs is pre-scaled by dinv (in GEMM epilogue).
// out[n,f4] = dinv[n] * (Hs[n,f4] + sum_s Hs[s,f4]) + b[f4]; optional relu.

template <int M, bool RELU>
__global__ __launch_bounds__(256) void k_agg(const float* __restrict__ Hs,
                                             const int* __restrict__ csr,
                                             const int* __restrict__ rs,
                                             const int* __restrict__ cnt,
                                             const float* __restrict__ dinv,
                                             const float* __restrict__ bias,
                                             float* __restrict__ out, int N) {
  constexpr int JC = M / 4;
  int gid = blockIdx.x * blockDim.x + threadIdx.x;
  int n = gid / JC;
  if (n >= N) return;
  int f4 = (gid - n * JC) * 4;
  float dn = dinv[n];
  float4 acc = *(const float4*)(Hs + (size_t)n * M + f4);   // self-loop term
  int p = rs[n];
  int e = cnt[n];
  int i = 0;
  for (; i + 4 <= e; i += 4) {
    int s0 = csr[p + i];
    int s1 = csr[p + i + 1];
    int s2 = csr[p + i + 2];
    int s3 = csr[p + i + 3];
    float4 h0 = *(const float4*)(Hs + (size_t)s0 * M + f4);
    float4 h1 = *(const float4*)(Hs + (size_t)s1 * M + f4);
    float4 h2 = *(const float4*)(Hs + (size_t)s2 * M + f4);
    float4 h3 = *(const float4*)(Hs + (size_t)s3 * M + f4);
    acc.x += (h0.x + h1.x) + (h2.x + h3.x);
    acc.y += (h0.y + h1.y) + (h2.y + h3.y);
    acc.z += (h0.z + h1.z) + (h2.z + h3.z);
    acc.w += (h0.w + h1.w) + (h2.w + h3.w);
  }
  for (; i < e; ++i) {
    int s = csr[p + i];
    float4 h = *(const float4*)(Hs + (size_t)s * M + f4);
    acc.x += h.x; acc.y += h.y; acc.z += h.z; acc.w += h.w;
  }
  float4 b = *(const float4*)(bias + f4);
  float4 r;
  r.x = fmaf(dn, acc.x, b.x);
  r.y = fmaf(dn, acc.y, b.y);
  r.z = fmaf(dn, acc.z, b.z);
  r.w = fmaf(dn, acc.w, b.w);
  if (RELU) {
    r.x = fmaxf(r.x, 0.0f); r.y = fmaxf(r.y, 0.0f);
    r.z = fmaxf(r.z, 0.0f); r.w = fmaxf(r.w, 0.0f);
  }
  *(float4*)(out + (size_t)n * M + f4) = r;
}

// ---------------- launch ----------------

extern "C" void kernel_launch(void* const* d_in, const int* in_sizes, int n_in,
                              void* d_out, int out_size, void* d_ws, size_t ws_size,
                              hipStream_t stream) {
  const float* x  = (const float*)d_in[0];
  const int*   ei = (const int*)d_in[1];
  const float* W1 = (const float*)d_in[2];
  const float* b1 = (const float*)d_in[3];
  const float* W2 = (const float*)d_in[4];
  const float* b2 = (const float*)d_in[5];
  float* out = (float*)d_out;

  const int N = in_sizes[0] / IN_C;     // 50000
  const int E = in_sizes[1] / 2;        // 800000
  const int* src = ei;
  const int* dst = ei + E;

  char* ws = (char*)d_ws;
  size_t off = 0;
  auto alloc = [&](size_t bytes) -> void* {
    void* p = ws + off;
    off = (off + bytes + 255) & ~(size_t)255;
    return p;
  };
  int*   cnt    = (int*)alloc((size_t)N * 4);
  int*   rs     = (int*)alloc((size_t)N * 4);
  float* dinv   = (float*)alloc((size_t)N * 4);
  int*   bsum   = (int*)alloc(256 * 4);
  int*   boff   = (int*)alloc(256 * 4);
  int*   junk   = (int*)alloc(256 * 4);
  int*   perm   = (int*)alloc((size_t)E * 4);
  int*   csr    = (int*)alloc((size_t)E * 4);
  float* h1     = (float*)alloc((size_t)N * HID * 4);   // reused as h2 later
  float* h      = (float*)alloc((size_t)N * HID * 4);

  const int nbN = (N + 255) / 256;
  const int nbE = (E + 255) / 256;
  const int P   = (N + NPART - 1) / NPART;

  hipMemsetAsync(cnt, 0, (size_t)N * 4, stream);
  k_count<<<nbE, 256, 0, stream>>>(dst, cnt, perm, E);
  k_scan_block<<<nbN, 256, 0, stream>>>(cnt, rs, bsum, N);
  k_scan_block<<<1, 256, 0, stream>>>(bsum, boff, junk, nbN);
  k_finish<<<nbN, 256, 0, stream>>>(rs, boff, cnt, dinv, N);
  dim3 fg(NPART, (E + CHUNK - 1) / CHUNK);
  k_fill_part<<<fg, 256, 0, stream>>>(src, dst, perm, rs, csr, E, P);

  const int rowBlocks = (N + 63) / 64;   // 782

  // layer 1: h1 = dinv * (x @ W1) ; h = relu(dinv*(agg(h1)) + b1)
  {
    // JC=24 col-chunks, 384/24=16 row-groups, R=4 rows each
    k_gemm<IN_C, HID, 24, 4><<<rowBlocks, 384, 0, stream>>>(x, W1, dinv, h1, N);
    int t2 = N * (HID / 4);
    k_agg<HID, true><<<(t2 + 255) / 256, 256, 0, stream>>>(h1, csr, rs, cnt, dinv, b1, h, N);
  }
  // layer 2: h2 = dinv * (h @ W2) (into h1 buffer) ; out = dinv*agg(h2) + b2
  {
    // JC=12 col-chunks, 384/12=32 row-groups, R=2 rows each
    k_gemm<HID, OUT_C, 12, 2><<<rowBlocks, 384, 0, stream>>>(h, W2, dinv, h1, N);
    int t2 = N * (OUT_C / 4);
    k_agg<OUT_C, false><<<(t2 + 255) / 256, 256, 0, stream>>>(h1, csr, rs, cnt, dinv, b2, out, N);
  }
}

// Round 12
// 167.828 us; speedup vs baseline: 1.4534x; 1.1486x over previous
//
#include <hip/hip_runtime.h>

static constexpr int IN_C  = 128;
static constexpr int HID   = 96;
static constexpr int OUT_C = 48;

static constexpr int NPART     = 8;     // XCD count on MI355X (perf heuristic only)
static constexpr int FILL_ITER = 16;
static constexpr int CHUNK     = 256 * FILL_ITER;  // edges per chunk

// ---------------- bf16 helpers ----------------

__device__ __forceinline__ unsigned short f2bf(float f) {   // RNE pack
  union { float f; unsigned u; } c; c.f = f;
  unsigned r = c.u + 0x7fffu + ((c.u >> 16) & 1u);
  return (unsigned short)(r >> 16);
}
__device__ __forceinline__ float bflo(unsigned u) {
  union { unsigned u; float f; } c; c.u = u << 16; return c.f;
}
__device__ __forceinline__ float bfhi(unsigned u) {
  union { unsigned u; float f; } c; c.u = u & 0xffff0000u; return c.f;
}

// ---------------- CSR build ----------------

__global__ void k_count(const int* __restrict__ dst, int* __restrict__ cnt,
                        int* __restrict__ perm, int E) {
  int e = blockIdx.x * blockDim.x + threadIdx.x;
  if (e < E) perm[e] = atomicAdd(&cnt[dst[e]], 1);
}

__global__ void k_scan_block(const int* __restrict__ in, int* __restrict__ out_excl,
                             int* __restrict__ bsum, int n) {
  __shared__ int sm[256];
  int i = blockIdx.x * 256 + threadIdx.x;
  int v = (i < n) ? in[i] : 0;
  int val = v;
  sm[threadIdx.x] = val;
  __syncthreads();
  for (int off = 1; off < 256; off <<= 1) {
    int t = (threadIdx.x >= (unsigned)off) ? sm[threadIdx.x - off] : 0;
    __syncthreads();
    val += t;
    sm[threadIdx.x] = val;
    __syncthreads();
  }
  if (i < n) out_excl[i] = val - v;
  if (threadIdx.x == 255) bsum[blockIdx.x] = val;
}

__global__ void k_finish(int* __restrict__ rs, const int* __restrict__ boff,
                         const int* __restrict__ cnt,
                         float* __restrict__ dinv, int n) {
  int i = blockIdx.x * 256 + threadIdx.x;
  if (i >= n) return;
  rs[i] = rs[i] + boff[blockIdx.x];
  dinv[i] = rsqrtf((float)cnt[i] + 1.0f);
}

__global__ __launch_bounds__(256) void k_fill_part(
    const int* __restrict__ src, const int* __restrict__ dst,
    const int* __restrict__ perm, const int* __restrict__ rs,
    int* __restrict__ csr, int E, int P) {
  int lo = blockIdx.x * P;
  int hi = lo + P;
  int base = blockIdx.y * CHUNK + threadIdx.x;
#pragma unroll
  for (int i = 0; i < FILL_ITER; ++i) {
    int e = base + i * 256;
    if (e < E) {
      int d = dst[e];
      if (d >= lo && d < hi) {
        csr[rs[d] + perm[e]] = src[e];
      }
    }
  }
}

// ---------------- GEMM: Y[N x M] = dinv[r] * (X[N x K] @ W[K x M]) ----------------
// LDS-staged (round-11 structure, verified). OBF16: epilogue packs bf16 rows
// (halves the gather payload for the following aggregation).

__device__ __forceinline__ void fma4(float4& a, float s, const float4& w) {
  a.x = fmaf(s, w.x, a.x); a.y = fmaf(s, w.y, a.y);
  a.z = fmaf(s, w.z, a.z); a.w = fmaf(s, w.w, a.w);
}

template <int K, int M, int JC, int R, bool OBF16>
__global__ __launch_bounds__(384) void k_gemm(const float* __restrict__ X,
                                              const float* __restrict__ W,
                                              const float* __restrict__ dinv,
                                              void* __restrict__ Yv, int N) {
  static_assert(384 % JC == 0 && (384 / JC) * R == 64, "tile mapping");
  constexpr int STRIDE = K + 4;
  __shared__ float lds[64 * STRIDE];
  const int tid  = threadIdx.x;
  const int base = blockIdx.x * 64;

  constexpr int KC = K / 4;
  constexpr int NF4 = 64 * KC;
  for (int idx = tid; idx < NF4; idx += 384) {
    int row = idx / KC;
    int kc  = idx - row * KC;
    int srow = min(base + row, N - 1);
    float4 v = *(const float4*)(X + (size_t)srow * K + kc * 4);
    *(float4*)(&lds[row * STRIDE + kc * 4]) = v;
  }
  __syncthreads();

  const int jc = (tid % JC) * 4;
  const int rg = tid / JC;
  float4 acc[R] = {};

#pragma unroll 2
  for (int k = 0; k < K; k += 4) {
    const float* wk = W + (size_t)k * M + jc;
    float4 w0 = *(const float4*)(wk);
    float4 w1 = *(const float4*)(wk + M);
    float4 w2 = *(const float4*)(wk + 2 * M);
    float4 w3 = *(const float4*)(wk + 3 * M);
#pragma unroll
    for (int i = 0; i < R; ++i) {
      float4 xv = *(const float4*)(&lds[(rg * R + i) * STRIDE + k]);
      fma4(acc[i], xv.x, w0);
      fma4(acc[i], xv.y, w1);
      fma4(acc[i], xv.z, w2);
      fma4(acc[i], xv.w, w3);
    }
  }

#pragma unroll
  for (int i = 0; i < R; ++i) {
    int row = base + rg * R + i;
    if (row < N) {
      float d = dinv[row];
      float4 o = make_float4(acc[i].x * d, acc[i].y * d, acc[i].z * d, acc[i].w * d);
      if (OBF16) {
        ushort4 ob;
        ob.x = f2bf(o.x); ob.y = f2bf(o.y); ob.z = f2bf(o.z); ob.w = f2bf(o.w);
        *(ushort4*)((unsigned short*)Yv + (size_t)row * M + jc) = ob;
      } else {
        *(float4*)((float*)Yv + (size_t)row * M + jc) = o;
      }
    }
  }
}

// ---------------- Aggregation (bf16 gathers) ----------------
// Hs: bf16, dinv-prescaled. Thread owns (node, 8 features): one uint4 gather
// = 8 bf16 features. out[n,f8..] = dinv[n]*(Hs[n]+sum_s Hs[s]) + b; opt relu.

__device__ __forceinline__ void bfacc(float* a, const uint4& v) {
  a[0] += bflo(v.x); a[1] += bfhi(v.x);
  a[2] += bflo(v.y); a[3] += bfhi(v.y);
  a[4] += bflo(v.z); a[5] += bfhi(v.z);
  a[6] += bflo(v.w); a[7] += bfhi(v.w);
}

template <int M, bool RELU>
__global__ __launch_bounds__(256) void k_agg(const unsigned short* __restrict__ Hs,
                                             const int* __restrict__ csr,
                                             const int* __restrict__ rs,
                                             const int* __restrict__ cnt,
                                             const float* __restrict__ dinv,
                                             const float* __restrict__ bias,
                                             float* __restrict__ out, int N) {
  constexpr int JC = M / 8;
  int gid = blockIdx.x * blockDim.x + threadIdx.x;
  int n = gid / JC;
  if (n >= N) return;
  int f8 = (gid - n * JC) * 8;
  float dn = dinv[n];
  float a[8] = {};
  {
    uint4 sv = *(const uint4*)(Hs + (size_t)n * M + f8);   // self-loop term
    bfacc(a, sv);
  }
  int p = rs[n];
  int e = cnt[n];
  int i = 0;
  for (; i + 4 <= e; i += 4) {
    int s0 = csr[p + i];
    int s1 = csr[p + i + 1];
    int s2 = csr[p + i + 2];
    int s3 = csr[p + i + 3];
    uint4 g0 = *(const uint4*)(Hs + (size_t)s0 * M + f8);
    uint4 g1 = *(const uint4*)(Hs + (size_t)s1 * M + f8);
    uint4 g2 = *(const uint4*)(Hs + (size_t)s2 * M + f8);
    uint4 g3 = *(const uint4*)(Hs + (size_t)s3 * M + f8);
    bfacc(a, g0); bfacc(a, g1); bfacc(a, g2); bfacc(a, g3);
  }
  for (; i < e; ++i) {
    int s = csr[p + i];
    uint4 g = *(const uint4*)(Hs + (size_t)s * M + f8);
    bfacc(a, g);
  }
  float4 b0 = *(const float4*)(bias + f8);
  float4 b1 = *(const float4*)(bias + f8 + 4);
  float4 r0, r1;
  r0.x = fmaf(dn, a[0], b0.x); r0.y = fmaf(dn, a[1], b0.y);
  r0.z = fmaf(dn, a[2], b0.z); r0.w = fmaf(dn, a[3], b0.w);
  r1.x = fmaf(dn, a[4], b1.x); r1.y = fmaf(dn, a[5], b1.y);
  r1.z = fmaf(dn, a[6], b1.z); r1.w = fmaf(dn, a[7], b1.w);
  if (RELU) {
    r0.x = fmaxf(r0.x, 0.0f); r0.y = fmaxf(r0.y, 0.0f);
    r0.z = fmaxf(r0.z, 0.0f); r0.w = fmaxf(r0.w, 0.0f);
    r1.x = fmaxf(r1.x, 0.0f); r1.y = fmaxf(r1.y, 0.0f);
    r1.z = fmaxf(r1.z, 0.0f); r1.w = fmaxf(r1.w, 0.0f);
  }
  float* op = out + (size_t)n * M + f8;
  *(float4*)(op)     = r0;
  *(float4*)(op + 4) = r1;
}

// ---------------- launch ----------------

extern "C" void kernel_launch(void* const* d_in, const int* in_sizes, int n_in,
                              void* d_out, int out_size, void* d_ws, size_t ws_size,
                              hipStream_t stream) {
  const float* x  = (const float*)d_in[0];
  const int*   ei = (const int*)d_in[1];
  const float* W1 = (const float*)d_in[2];
  const float* b1 = (const float*)d_in[3];
  const float* W2 = (const float*)d_in[4];
  const float* b2 = (const float*)d_in[5];
  float* out = (float*)d_out;

  const int N = in_sizes[0] / IN_C;     // 50000
  const int E = in_sizes[1] / 2;        // 800000
  const int* src = ei;
  const int* dst = ei + E;

  char* ws = (char*)d_ws;
  size_t off = 0;
  auto alloc = [&](size_t bytes) -> void* {
    void* p = ws + off;
    off = (off + bytes + 255) & ~(size_t)255;
    return p;
  };
  int*   cnt    = (int*)alloc((size_t)N * 4);
  int*   rs     = (int*)alloc((size_t)N * 4);
  float* dinv   = (float*)alloc((size_t)N * 4);
  int*   bsum   = (int*)alloc(256 * 4);
  int*   boff   = (int*)alloc(256 * 4);
  int*   junk   = (int*)alloc(256 * 4);
  int*   perm   = (int*)alloc((size_t)E * 4);
  int*   csr    = (int*)alloc((size_t)E * 4);
  unsigned short* hbf = (unsigned short*)alloc((size_t)N * HID * 2); // h1/h2 bf16
  float* h      = (float*)alloc((size_t)N * HID * 4);                // agg1 out (fp32)

  const int nbN = (N + 255) / 256;
  const int nbE = (E + 255) / 256;
  const int P   = (N + NPART - 1) / NPART;

  hipMemsetAsync(cnt, 0, (size_t)N * 4, stream);
  k_count<<<nbE, 256, 0, stream>>>(dst, cnt, perm, E);
  k_scan_block<<<nbN, 256, 0, stream>>>(cnt, rs, bsum, N);
  k_scan_block<<<1, 256, 0, stream>>>(bsum, boff, junk, nbN);
  k_finish<<<nbN, 256, 0, stream>>>(rs, boff, cnt, dinv, N);
  dim3 fg(NPART, (E + CHUNK - 1) / CHUNK);
  k_fill_part<<<fg, 256, 0, stream>>>(src, dst, perm, rs, csr, E, P);

  const int rowBlocks = (N + 63) / 64;   // 782

  // layer 1: hbf = bf16(dinv * (x @ W1)) ; h = relu(dinv*agg(hbf) + b1)
  {
    k_gemm<IN_C, HID, 24, 4, true><<<rowBlocks, 384, 0, stream>>>(x, W1, dinv, hbf, N);
    int t = N * (HID / 8);
    k_agg<HID, true><<<(t + 255) / 256, 256, 0, stream>>>(hbf, csr, rs, cnt, dinv, b1, h, N);
  }
  // layer 2: hbf = bf16(dinv * (h @ W2)) ; out = dinv*agg(hbf) + b2
  {
    k_gemm<HID, OUT_C, 12, 2, true><<<rowBlocks, 384, 0, stream>>>(h, W2, dinv, hbf, N);
    int t = N * (OUT_C / 8);
    k_agg<OUT_C, false><<<(t + 255) / 256, 256, 0, stream>>>(hbf, csr, rs, cnt, dinv, b2, out, N);
  }
}

// Round 13
// 166.282 us; speedup vs baseline: 1.4669x; 1.0093x over previous
//
#include <hip/hip_runtime.h>

static constexpr int IN_C  = 128;
static constexpr int HID   = 96;
static constexpr int OUT_C = 48;

static constexpr int NPART     = 8;     // XCD count on MI355X (perf heuristic only)
static constexpr int FILL_ITER = 16;
static constexpr int CHUNK     = 256 * FILL_ITER;  // edges per chunk

// ---------------- bf16 helpers ----------------

__device__ __forceinline__ unsigned short f2bf(float f) {   // RNE pack
  union { float f; unsigned u; } c; c.f = f;
  unsigned r = c.u + 0x7fffu + ((c.u >> 16) & 1u);
  return (unsigned short)(r >> 16);
}
__device__ __forceinline__ float bflo(unsigned u) {
  union { unsigned u; float f; } c; c.u = u << 16; return c.f;
}
__device__ __forceinline__ float bfhi(unsigned u) {
  union { unsigned u; float f; } c; c.u = u & 0xffff0000u; return c.f;
}

// ---------------- utility ----------------

__global__ void k_zero(int* __restrict__ p, int n) {
  int i = blockIdx.x * blockDim.x + threadIdx.x;
  if (i < n) p[i] = 0;
}

// ---------------- CSR build ----------------

__global__ void k_count(const int* __restrict__ dst, int* __restrict__ cnt,
                        int* __restrict__ perm, int E) {
  int e = blockIdx.x * blockDim.x + threadIdx.x;
  if (e < E) perm[e] = atomicAdd(&cnt[dst[e]], 1);
}

__global__ void k_scan_block(const int* __restrict__ in, int* __restrict__ out_excl,
                             int* __restrict__ bsum, int n) {
  __shared__ int sm[256];
  int i = blockIdx.x * 256 + threadIdx.x;
  int v = (i < n) ? in[i] : 0;
  int val = v;
  sm[threadIdx.x] = val;
  __syncthreads();
  for (int off = 1; off < 256; off <<= 1) {
    int t = (threadIdx.x >= (unsigned)off) ? sm[threadIdx.x - off] : 0;
    __syncthreads();
    val += t;
    sm[threadIdx.x] = val;
    __syncthreads();
  }
  if (i < n) out_excl[i] = val - v;
  if (threadIdx.x == 255) bsum[blockIdx.x] = val;
}

__global__ void k_finish(int* __restrict__ rs, const int* __restrict__ boff,
                         const int* __restrict__ cnt,
                         float* __restrict__ dinv, int n) {
  int i = blockIdx.x * 256 + threadIdx.x;
  if (i >= n) return;
  rs[i] = rs[i] + boff[blockIdx.x];
  dinv[i] = rsqrtf((float)cnt[i] + 1.0f);
}

__global__ __launch_bounds__(256) void k_fill_part(
    const int* __restrict__ src, const int* __restrict__ dst,
    const int* __restrict__ perm, const int* __restrict__ rs,
    int* __restrict__ csr, int E, int P) {
  int lo = blockIdx.x * P;
  int hi = lo + P;
  int base = blockIdx.y * CHUNK + threadIdx.x;
#pragma unroll
  for (int i = 0; i < FILL_ITER; ++i) {
    int e = base + i * 256;
    if (e < E) {
      int d = dst[e];
      if (d >= lo && d < hi) {
        csr[rs[d] + perm[e]] = src[e];
      }
    }
  }
}

// ---------------- GEMM: Y[N x M] = dinv[r] * (X[N x K] @ W[K x M]) ----------------
// LDS-staged 64-row tile (round-11 structure). Manual register double-buffer:
// chunk k+4's W panel + X lds rows are issued BEFORE chunk k's FMAs, so loads
// stay in flight across the FMA cluster (counted waits instead of drain).

__device__ __forceinline__ void fma4(float4& a, float s, const float4& w) {
  a.x = fmaf(s, w.x, a.x); a.y = fmaf(s, w.y, a.y);
  a.z = fmaf(s, w.z, a.z); a.w = fmaf(s, w.w, a.w);
}

template <int K, int M, int JC, int R, bool OBF16>
__global__ __launch_bounds__(384) void k_gemm(const float* __restrict__ X,
                                              const float* __restrict__ W,
                                              const float* __restrict__ dinv,
                                              void* __restrict__ Yv, int N) {
  static_assert(384 % JC == 0 && (384 / JC) * R == 64, "tile mapping");
  constexpr int STRIDE = K + 4;
  __shared__ float lds[64 * STRIDE];
  const int tid  = threadIdx.x;
  const int base = blockIdx.x * 64;

  constexpr int KC = K / 4;
  constexpr int NF4 = 64 * KC;
  for (int idx = tid; idx < NF4; idx += 384) {
    int row = idx / KC;
    int kc  = idx - row * KC;
    int srow = min(base + row, N - 1);
    float4 v = *(const float4*)(X + (size_t)srow * K + kc * 4);
    *(float4*)(&lds[row * STRIDE + kc * 4]) = v;
  }
  __syncthreads();

  const int jc = (tid % JC) * 4;
  const int rg = tid / JC;
  float4 acc[R] = {};

  // prologue: load chunk 0
  float4 cw0, cw1, cw2, cw3;
  float4 cx[R];
  {
    const float* wk = W + jc;
    cw0 = *(const float4*)(wk);
    cw1 = *(const float4*)(wk + M);
    cw2 = *(const float4*)(wk + 2 * M);
    cw3 = *(const float4*)(wk + 3 * M);
#pragma unroll
    for (int i = 0; i < R; ++i)
      cx[i] = *(const float4*)(&lds[(rg * R + i) * STRIDE]);
  }

#pragma unroll 2
  for (int k = 0; k < K; k += 4) {
    const int kn = (k + 4 < K) ? (k + 4) : 0;   // last iter: redundant reload of 0
    // issue next chunk's loads first
    const float* wn = W + (size_t)kn * M + jc;
    float4 nw0 = *(const float4*)(wn);
    float4 nw1 = *(const float4*)(wn + M);
    float4 nw2 = *(const float4*)(wn + 2 * M);
    float4 nw3 = *(const float4*)(wn + 3 * M);
    float4 nx[R];
#pragma unroll
    for (int i = 0; i < R; ++i)
      nx[i] = *(const float4*)(&lds[(rg * R + i) * STRIDE + kn]);
    // FMAs on current chunk
#pragma unroll
    for (int i = 0; i < R; ++i) {
      fma4(acc[i], cx[i].x, cw0);
      fma4(acc[i], cx[i].y, cw1);
      fma4(acc[i], cx[i].z, cw2);
      fma4(acc[i], cx[i].w, cw3);
    }
    cw0 = nw0; cw1 = nw1; cw2 = nw2; cw3 = nw3;
#pragma unroll
    for (int i = 0; i < R; ++i) cx[i] = nx[i];
  }

#pragma unroll
  for (int i = 0; i < R; ++i) {
    int row = base + rg * R + i;
    if (row < N) {
      float d = dinv[row];
      float4 o = make_float4(acc[i].x * d, acc[i].y * d, acc[i].z * d, acc[i].w * d);
      if (OBF16) {
        ushort4 ob;
        ob.x = f2bf(o.x); ob.y = f2bf(o.y); ob.z = f2bf(o.z); ob.w = f2bf(o.w);
        *(ushort4*)((unsigned short*)Yv + (size_t)row * M + jc) = ob;
      } else {
        *(float4*)((float*)Yv + (size_t)row * M + jc) = o;
      }
    }
  }
}

// ---------------- Aggregation (bf16 gathers) ----------------

__device__ __forceinline__ void bfacc(float* a, const uint4& v) {
  a[0] += bflo(v.x); a[1] += bfhi(v.x);
  a[2] += bflo(v.y); a[3] += bfhi(v.y);
  a[4] += bflo(v.z); a[5] += bfhi(v.z);
  a[6] += bflo(v.w); a[7] += bfhi(v.w);
}

template <int M, bool RELU>
__global__ __launch_bounds__(256) void k_agg(const unsigned short* __restrict__ Hs,
                                             const int* __restrict__ csr,
                                             const int* __restrict__ rs,
                                             const int* __restrict__ cnt,
                                             const float* __restrict__ dinv,
                                             const float* __restrict__ bias,
                                             float* __restrict__ out, int N) {
  constexpr int JC = M / 8;
  int gid = blockIdx.x * blockDim.x + threadIdx.x;
  int n = gid / JC;
  if (n >= N) return;
  int f8 = (gid - n * JC) * 8;
  float dn = dinv[n];
  float a[8] = {};
  {
    uint4 sv = *(const uint4*)(Hs + (size_t)n * M + f8);   // self-loop term
    bfacc(a, sv);
  }
  int p = rs[n];
  int e = cnt[n];
  int i = 0;
  for (; i + 4 <= e; i += 4) {
    int s0 = csr[p + i];
    int s1 = csr[p + i + 1];
    int s2 = csr[p + i + 2];
    int s3 = csr[p + i + 3];
    uint4 g0 = *(const uint4*)(Hs + (size_t)s0 * M + f8);
    uint4 g1 = *(const uint4*)(Hs + (size_t)s1 * M + f8);
    uint4 g2 = *(const uint4*)(Hs + (size_t)s2 * M + f8);
    uint4 g3 = *(const uint4*)(Hs + (size_t)s3 * M + f8);
    bfacc(a, g0); bfacc(a, g1); bfacc(a, g2); bfacc(a, g3);
  }
  for (; i < e; ++i) {
    int s = csr[p + i];
    uint4 g = *(const uint4*)(Hs + (size_t)s * M + f8);
    bfacc(a, g);
  }
  float4 b0 = *(const float4*)(bias + f8);
  float4 b1 = *(const float4*)(bias + f8 + 4);
  float4 r0, r1;
  r0.x = fmaf(dn, a[0], b0.x); r0.y = fmaf(dn, a[1], b0.y);
  r0.z = fmaf(dn, a[2], b0.z); r0.w = fmaf(dn, a[3], b0.w);
  r1.x = fmaf(dn, a[4], b1.x); r1.y = fmaf(dn, a[5], b1.y);
  r1.z = fmaf(dn, a[6], b1.z); r1.w = fmaf(dn, a[7], b1.w);
  if (RELU) {
    r0.x = fmaxf(r0.x, 0.0f); r0.y = fmaxf(r0.y, 0.0f);
    r0.z = fmaxf(r0.z, 0.0f); r0.w = fmaxf(r0.w, 0.0f);
    r1.x = fmaxf(r1.x, 0.0f); r1.y = fmaxf(r1.y, 0.0f);
    r1.z = fmaxf(r1.z, 0.0f); r1.w = fmaxf(r1.w, 0.0f);
  }
  float* op = out + (size_t)n * M + f8;
  *(float4*)(op)     = r0;
  *(float4*)(op + 4) = r1;
}

// ---------------- launch ----------------

extern "C" void kernel_launch(void* const* d_in, const int* in_sizes, int n_in,
                              void* d_out, int out_size, void* d_ws, size_t ws_size,
                              hipStream_t stream) {
  const float* x  = (const float*)d_in[0];
  const int*   ei = (const int*)d_in[1];
  const float* W1 = (const float*)d_in[2];
  const float* b1 = (const float*)d_in[3];
  const float* W2 = (const float*)d_in[4];
  const float* b2 = (const float*)d_in[5];
  float* out = (float*)d_out;

  const int N = in_sizes[0] / IN_C;     // 50000
  const int E = in_sizes[1] / 2;        // 800000
  const int* src = ei;
  const int* dst = ei + E;

  char* ws = (char*)d_ws;
  size_t off = 0;
  auto alloc = [&](size_t bytes) -> void* {
    void* p = ws + off;
    off = (off + bytes + 255) & ~(size_t)255;
    return p;
  };
  int*   cnt    = (int*)alloc((size_t)N * 4);
  int*   rs     = (int*)alloc((size_t)N * 4);
  float* dinv   = (float*)alloc((size_t)N * 4);
  int*   bsum   = (int*)alloc(256 * 4);
  int*   boff   = (int*)alloc(256 * 4);
  int*   junk   = (int*)alloc(256 * 4);
  int*   perm   = (int*)alloc((size_t)E * 4);
  int*   csr    = (int*)alloc((size_t)E * 4);
  unsigned short* hbf = (unsigned short*)alloc((size_t)N * HID * 2); // h1/h2 bf16
  float* h      = (float*)alloc((size_t)N * HID * 4);                // agg1 out (fp32)

  const int nbN = (N + 255) / 256;
  const int nbE = (E + 255) / 256;
  const int P   = (N + NPART - 1) / NPART;

  k_zero<<<nbN, 256, 0, stream>>>(cnt, N);
  k_count<<<nbE, 256, 0, stream>>>(dst, cnt, perm, E);
  k_scan_block<<<nbN, 256, 0, stream>>>(cnt, rs, bsum, N);
  k_scan_block<<<1, 256, 0, stream>>>(bsum, boff, junk, nbN);
  k_finish<<<nbN, 256, 0, stream>>>(rs, boff, cnt, dinv, N);
  dim3 fg(NPART, (E + CHUNK - 1) / CHUNK);
  k_fill_part<<<fg, 256, 0, stream>>>(src, dst, perm, rs, csr, E, P);

  const int rowBlocks = (N + 63) / 64;   // 782

  // layer 1: hbf = bf16(dinv * (x @ W1)) ; h = relu(dinv*agg(hbf) + b1)
  {
    k_gemm<IN_C, HID, 24, 4, true><<<rowBlocks, 384, 0, stream>>>(x, W1, dinv, hbf, N);
    int t = N * (HID / 8);
    k_agg<HID, true><<<(t + 255) / 256, 256, 0, stream>>>(hbf, csr, rs, cnt, dinv, b1, h, N);
  }
  // layer 2: hbf = bf16(dinv * (h @ W2)) ; out = dinv*agg(hbf) + b2
  {
    k_gemm<HID, OUT_C, 12, 2, true><<<rowBlocks, 384, 0, stream>>>(h, W2, dinv, hbf, N);
    int t = N * (OUT_C / 8);
    k_agg<OUT_C, false><<<(t + 255) / 256, 256, 0, stream>>>(hbf, csr, rs, cnt, dinv, b2, out, N);
  }
}

// Round 14
// 163.644 us; speedup vs baseline: 1.4905x; 1.0161x over previous
//
#include <hip/hip_runtime.h>

static constexpr int IN_C  = 128;
static constexpr int HID   = 96;
static constexpr int OUT_C = 48;

static constexpr int NPART     = 8;
static constexpr int FILL_ITER = 16;
static constexpr int CHUNK     = 256 * FILL_ITER;

// ---------------- bf16 helpers ----------------

__device__ __forceinline__ unsigned short f2bf(float f) {   // RNE pack
  union { float f; unsigned u; } c; c.f = f;
  unsigned r = c.u + 0x7fffu + ((c.u >> 16) & 1u);
  return (unsigned short)(r >> 16);
}
__device__ __forceinline__ float bflo(unsigned u) {
  union { unsigned u; float f; } c; c.u = u << 16; return c.f;
}
__device__ __forceinline__ float bfhi(unsigned u) {
  union { unsigned u; float f; } c; c.u = u & 0xffff0000u; return c.f;
}

// ---------------- utility ----------------

__global__ void k_zero(int* __restrict__ p, int n) {
  int i = blockIdx.x * blockDim.x + threadIdx.x;
  if (i < n) p[i] = 0;
}

// ---------------- CSR build ----------------

__global__ void k_count(const int* __restrict__ dst, int* __restrict__ cnt,
                        int* __restrict__ perm, int E) {
  int e = blockIdx.x * blockDim.x + threadIdx.x;
  if (e < E) perm[e] = atomicAdd(&cnt[dst[e]], 1);
}

__global__ void k_scan_block(const int* __restrict__ in, int* __restrict__ out_excl,
                             int* __restrict__ bsum, int n) {
  __shared__ int sm[256];
  int i = blockIdx.x * 256 + threadIdx.x;
  int v = (i < n) ? in[i] : 0;
  int val = v;
  sm[threadIdx.x] = val;
  __syncthreads();
  for (int off = 1; off < 256; off <<= 1) {
    int t = (threadIdx.x >= (unsigned)off) ? sm[threadIdx.x - off] : 0;
    __syncthreads();
    val += t;
    sm[threadIdx.x] = val;
    __syncthreads();
  }
  if (i < n) out_excl[i] = val - v;
  if (threadIdx.x == 255) bsum[blockIdx.x] = val;
}

__global__ void k_finish(int* __restrict__ rs, const int* __restrict__ boff,
                         const int* __restrict__ cnt,
                         float* __restrict__ dinv, int n) {
  int i = blockIdx.x * 256 + threadIdx.x;
  if (i >= n) return;
  rs[i] = rs[i] + boff[blockIdx.x];
  dinv[i] = rsqrtf((float)cnt[i] + 1.0f);
}

__global__ __launch_bounds__(256) void k_fill_part(
    const int* __restrict__ src, const int* __restrict__ dst,
    const int* __restrict__ perm, const int* __restrict__ rs,
    int* __restrict__ csr, int E, int P) {
  int lo = blockIdx.x * P;
  int hi = lo + P;
  int base = blockIdx.y * CHUNK + threadIdx.x;
#pragma unroll
  for (int i = 0; i < FILL_ITER; ++i) {
    int e = base + i * 256;
    if (e < E) {
      int d = dst[e];
      if (d >= lo && d < hi) {
        csr[rs[d] + perm[e]] = src[e];
      }
    }
  }
}

// ---------------- GEMM: Y = bf16(dinv[r] * (X @ W)) ----------------
// Scalar-W design: wave = 64 rows (lane = row) x CW cols; c0 is wave-uniform
// (readfirstlane) -> W loads scalarize to s_load (SGPR broadcast, scalar
// cache) and FMAs use SGPR operands. X staged in LDS with XOR swizzle
// kc' = (kc&~7)|((kc^row)&7): lane=row ds_read_b128 at row-stride K floats
// (K%32==0) spreads 8-row groups across all 32 banks -> conflict-free.
// Per 4-k chunk: 1 ds_read_b128 + 4 scalar W loads + 4*CW FMA.

template <int K, int M, int CW>
__global__ __launch_bounds__(384) void k_gemm(const float* __restrict__ X,
                                              const float* __restrict__ W,
                                              const float* __restrict__ dinv,
                                              unsigned short* __restrict__ Y,
                                              int N) {
  static_assert(6 * CW == M, "6 waves cover M");
  static_assert(K % 32 == 0, "row stride multiple of 32 floats");
  constexpr int KC4 = K / 4;
  __shared__ float lds[64 * K];
  const int tid  = threadIdx.x;
  const int base = blockIdx.x * 64;

  // ---- stage 64 rows x K, coalesced global read, XOR-swizzled LDS write ----
  constexpr int NF4 = 64 * KC4;
  for (int idx = tid; idx < NF4; idx += 384) {
    int row = idx / KC4;
    int kc  = idx - row * KC4;
    int srow = min(base + row, N - 1);
    float4 v = *(const float4*)(X + (size_t)srow * K + 4 * kc);
    int kcs = (kc & ~7) | ((kc ^ row) & 7);
    *(float4*)(&lds[row * K + 4 * kcs]) = v;
  }
  __syncthreads();

  const int lane = tid & 63;
  const int wv   = tid >> 6;                         // 0..5
  const int c0   = __builtin_amdgcn_readfirstlane(wv * CW);
  const float* Wp = W + c0;                          // wave-uniform

  float acc[CW];
#pragma unroll
  for (int c = 0; c < CW; ++c) acc[c] = 0.0f;

#pragma unroll 2
  for (int kc = 0; kc < KC4; ++kc) {
    int kcs = (kc & ~7) | ((kc ^ lane) & 7);
    float4 xv = *(const float4*)(&lds[lane * K + 4 * kcs]);
    const float* wr = Wp + (size_t)(4 * kc) * M;
#pragma unroll
    for (int c = 0; c < CW; ++c) {
      acc[c] = fmaf(xv.x, wr[c],         acc[c]);
      acc[c] = fmaf(xv.y, wr[M + c],     acc[c]);
      acc[c] = fmaf(xv.z, wr[2 * M + c], acc[c]);
      acc[c] = fmaf(xv.w, wr[3 * M + c], acc[c]);
    }
  }

  int row = base + lane;
  if (row < N) {
    float d = dinv[row];
    unsigned pk[CW / 2];
#pragma unroll
    for (int c = 0; c < CW; c += 2) {
      pk[c / 2] = (unsigned)f2bf(acc[c] * d) | ((unsigned)f2bf(acc[c + 1] * d) << 16);
    }
    unsigned short* yp = Y + (size_t)row * M + c0;
#pragma unroll
    for (int q = 0; q < CW / 8; ++q) {
      *(uint4*)(yp + q * 8) = *(uint4*)(&pk[q * 4]);
    }
  }
}

// ---------------- Aggregation (bf16 gathers) ----------------

__device__ __forceinline__ void bfacc(float* a, const uint4& v) {
  a[0] += bflo(v.x); a[1] += bfhi(v.x);
  a[2] += bflo(v.y); a[3] += bfhi(v.y);
  a[4] += bflo(v.z); a[5] += bfhi(v.z);
  a[6] += bflo(v.w); a[7] += bfhi(v.w);
}

template <int M, bool RELU>
__global__ __launch_bounds__(256) void k_agg(const unsigned short* __restrict__ Hs,
                                             const int* __restrict__ csr,
                                             const int* __restrict__ rs,
                                             const int* __restrict__ cnt,
                                             const float* __restrict__ dinv,
                                             const float* __restrict__ bias,
                                             float* __restrict__ out, int N) {
  constexpr int JC = M / 8;
  int gid = blockIdx.x * blockDim.x + threadIdx.x;
  int n = gid / JC;
  if (n >= N) return;
  int f8 = (gid - n * JC) * 8;
  float dn = dinv[n];
  float a[8] = {};
  {
    uint4 sv = *(const uint4*)(Hs + (size_t)n * M + f8);
    bfacc(a, sv);
  }
  int p = rs[n];
  int e = cnt[n];
  int i = 0;
  for (; i + 4 <= e; i += 4) {
    int s0 = csr[p + i];
    int s1 = csr[p + i + 1];
    int s2 = csr[p + i + 2];
    int s3 = csr[p + i + 3];
    uint4 g0 = *(const uint4*)(Hs + (size_t)s0 * M + f8);
    uint4 g1 = *(const uint4*)(Hs + (size_t)s1 * M + f8);
    uint4 g2 = *(const uint4*)(Hs + (size_t)s2 * M + f8);
    uint4 g3 = *(const uint4*)(Hs + (size_t)s3 * M + f8);
    bfacc(a, g0); bfacc(a, g1); bfacc(a, g2); bfacc(a, g3);
  }
  for (; i < e; ++i) {
    int s = csr[p + i];
    uint4 g = *(const uint4*)(Hs + (size_t)s * M + f8);
    bfacc(a, g);
  }
  float4 b0 = *(const float4*)(bias + f8);
  float4 b1 = *(const float4*)(bias + f8 + 4);
  float4 r0, r1;
  r0.x = fmaf(dn, a[0], b0.x); r0.y = fmaf(dn, a[1], b0.y);
  r0.z = fmaf(dn, a[2], b0.z); r0.w = fmaf(dn, a[3], b0.w);
  r1.x = fmaf(dn, a[4], b1.x); r1.y = fmaf(dn, a[5], b1.y);
  r1.z = fmaf(dn, a[6], b1.z); r1.w = fmaf(dn, a[7], b1.w);
  if (RELU) {
    r0.x = fmaxf(r0.x, 0.0f); r0.y = fmaxf(r0.y, 0.0f);
    r0.z = fmaxf(r0.z, 0.0f); r0.w = fmaxf(r0.w, 0.0f);
    r1.x = fmaxf(r1.x, 0.0f); r1.y = fmaxf(r1.y, 0.0f);
    r1.z = fmaxf(r1.z, 0.0f); r1.w = fmaxf(r1.w, 0.0f);
  }
  float* op = out + (size_t)n * M + f8;
  *(float4*)(op)     = r0;
  *(float4*)(op + 4) = r1;
}

// ---------------- launch ----------------

extern "C" void kernel_launch(void* const* d_in, const int* in_sizes, int n_in,
                              void* d_out, int out_size, void* d_ws, size_t ws_size,
                              hipStream_t stream) {
  const float* x  = (const float*)d_in[0];
  const int*   ei = (const int*)d_in[1];
  const float* W1 = (const float*)d_in[2];
  const float* b1 = (const float*)d_in[3];
  const float* W2 = (const float*)d_in[4];
  const float* b2 = (const float*)d_in[5];
  float* out = (float*)d_out;

  const int N = in_sizes[0] / IN_C;     // 50000
  const int E = in_sizes[1] / 2;        // 800000
  const int* src = ei;
  const int* dst = ei + E;

  char* ws = (char*)d_ws;
  size_t off = 0;
  auto alloc = [&](size_t bytes) -> void* {
    void* p = ws + off;
    off = (off + bytes + 255) & ~(size_t)255;
    return p;
  };
  int*   cnt    = (int*)alloc((size_t)N * 4);
  int*   rs     = (int*)alloc((size_t)N * 4);
  float* dinv   = (float*)alloc((size_t)N * 4);
  int*   bsum   = (int*)alloc(256 * 4);
  int*   boff   = (int*)alloc(256 * 4);
  int*   junk   = (int*)alloc(256 * 4);
  int*   perm   = (int*)alloc((size_t)E * 4);
  int*   csr    = (int*)alloc((size_t)E * 4);
  unsigned short* hbf = (unsigned short*)alloc((size_t)N * HID * 2);
  float* h      = (float*)alloc((size_t)N * HID * 4);

  const int nbN = (N + 255) / 256;
  const int nbE = (E + 255) / 256;
  const int P   = (N + NPART - 1) / NPART;

  k_zero<<<nbN, 256, 0, stream>>>(cnt, N);
  k_count<<<nbE, 256, 0, stream>>>(dst, cnt, perm, E);
  k_scan_block<<<nbN, 256, 0, stream>>>(cnt, rs, bsum, N);
  k_scan_block<<<1, 256, 0, stream>>>(bsum, boff, junk, nbN);
  k_finish<<<nbN, 256, 0, stream>>>(rs, boff, cnt, dinv, N);
  dim3 fg(NPART, (E + CHUNK - 1) / CHUNK);
  k_fill_part<<<fg, 256, 0, stream>>>(src, dst, perm, rs, csr, E, P);

  const int rowBlocks = (N + 63) / 64;   // 782

  // layer 1: hbf = bf16(dinv * (x @ W1)) ; h = relu(dinv*agg(hbf) + b1)
  {
    k_gemm<IN_C, HID, 16><<<rowBlocks, 384, 0, stream>>>(x, W1, dinv, hbf, N);
    int t = N * (HID / 8);
    k_agg<HID, true><<<(t + 255) / 256, 256, 0, stream>>>(hbf, csr, rs, cnt, dinv, b1, h, N);
  }
  // layer 2: hbf = bf16(dinv * (h @ W2)) ; out = dinv*agg(hbf) + b2
  {
    k_gemm<HID, OUT_C, 8><<<rowBlocks, 384, 0, stream>>>(h, W2, dinv, hbf, N);
    int t = N * (OUT_C / 8);
    k_agg<OUT_C, false><<<(t + 255) / 256, 256, 0, stream>>>(hbf, csr, rs, cnt, dinv, b2, out, N);
  }
}

// Round 15
// 131.743 us; speedup vs baseline: 1.8515x; 1.2421x over previous
//
#include <hip/hip_runtime.h>

static constexpr int IN_C  = 128;
static constexpr int HID   = 96;
static constexpr int OUT_C = 48;

static constexpr int NPART     = 8;
static constexpr int FILL_ITER = 16;
static constexpr int CHUNK     = 256 * FILL_ITER;

typedef short bf16x8 __attribute__((ext_vector_type(8)));
typedef float f32x4  __attribute__((ext_vector_type(4)));

// ---------------- bf16 helpers ----------------

__device__ __forceinline__ unsigned short f2bf(float f) {   // RNE pack
  union { float f; unsigned u; } c; c.f = f;
  unsigned r = c.u + 0x7fffu + ((c.u >> 16) & 1u);
  return (unsigned short)(r >> 16);
}
__device__ __forceinline__ float bflo(unsigned u) {
  union { unsigned u; float f; } c; c.u = u << 16; return c.f;
}
__device__ __forceinline__ float bfhi(unsigned u) {
  union { unsigned u; float f; } c; c.u = u & 0xffff0000u; return c.f;
}

// ---------------- utility ----------------

__global__ void k_zero(int* __restrict__ p, int n) {
  int i = blockIdx.x * blockDim.x + threadIdx.x;
  if (i < n) p[i] = 0;
}

// Pre-pack W (fp32 row-major [K][M]) into B-fragment order for 16x16x32 MFMA:
// entry ((c*KB + kb)*64 + lane) = 8 bf16 { W[kb*32+(lane>>4)*8+i][c*16+(lane&15)] }.
__device__ __forceinline__ void wprep_one(const float* W, uint4* Wt,
                                          int K, int M, int idx) {
  int lane = idx & 63;
  int t = idx >> 6;
  int KB = K / 32;
  int c  = t / KB;
  int kb = t - c * KB;
  int col = c * 16 + (lane & 15);
  int k0  = kb * 32 + (lane >> 4) * 8;
  unsigned pk[4];
#pragma unroll
  for (int q = 0; q < 4; ++q) {
    unsigned lo = f2bf(W[(size_t)(k0 + 2 * q) * M + col]);
    unsigned hi = f2bf(W[(size_t)(k0 + 2 * q + 1) * M + col]);
    pk[q] = lo | (hi << 16);
  }
  Wt[idx] = make_uint4(pk[0], pk[1], pk[2], pk[3]);
}

__global__ void k_wprep(const float* __restrict__ W1, uint4* __restrict__ Wt1, int T1,
                        const float* __restrict__ W2, uint4* __restrict__ Wt2, int T2) {
  int idx = blockIdx.x * blockDim.x + threadIdx.x;
  if (idx < T1) wprep_one(W1, Wt1, IN_C, HID, idx);
  else if (idx < T1 + T2) wprep_one(W2, Wt2, HID, OUT_C, idx - T1);
}

// ---------------- CSR build ----------------

__global__ void k_count(const int* __restrict__ dst, int* __restrict__ cnt,
                        int* __restrict__ perm, int E) {
  int e = blockIdx.x * blockDim.x + threadIdx.x;
  if (e < E) perm[e] = atomicAdd(&cnt[dst[e]], 1);
}

__global__ void k_scan_block(const int* __restrict__ in, int* __restrict__ out_excl,
                             int* __restrict__ bsum, int n) {
  __shared__ int sm[256];
  int i = blockIdx.x * 256 + threadIdx.x;
  int v = (i < n) ? in[i] : 0;
  int val = v;
  sm[threadIdx.x] = val;
  __syncthreads();
  for (int off = 1; off < 256; off <<= 1) {
    int t = (threadIdx.x >= (unsigned)off) ? sm[threadIdx.x - off] : 0;
    __syncthreads();
    val += t;
    sm[threadIdx.x] = val;
    __syncthreads();
  }
  if (i < n) out_excl[i] = val - v;
  if (threadIdx.x == 255) bsum[blockIdx.x] = val;
}

__global__ void k_finish(int* __restrict__ rs, const int* __restrict__ boff,
                         const int* __restrict__ cnt,
                         float* __restrict__ dinv, int n) {
  int i = blockIdx.x * 256 + threadIdx.x;
  if (i >= n) return;
  rs[i] = rs[i] + boff[blockIdx.x];
  dinv[i] = rsqrtf((float)cnt[i] + 1.0f);
}

__global__ __launch_bounds__(256) void k_fill_part(
    const int* __restrict__ src, const int* __restrict__ dst,
    const int* __restrict__ perm, const int* __restrict__ rs,
    int* __restrict__ csr, int E, int P) {
  int lo = blockIdx.x * P;
  int hi = lo + P;
  int base = blockIdx.y * CHUNK + threadIdx.x;
#pragma unroll
  for (int i = 0; i < FILL_ITER; ++i) {
    int e = base + i * 256;
    if (e < E) {
      int d = dst[e];
      if (d >= lo && d < hi) {
        csr[rs[d] + perm[e]] = src[e];
      }
    }
  }
}

// ---------------- MFMA GEMM: Y = bf16(dinv[r] * (X @ W)) ----------------
// 64-row block, 4 waves x 16 rows. A staged in LDS as bf16 (16B granules,
// XOR-swizzled j^=row&7 -> <=2-way conflicts on ds_read_b128). B from the
// pre-packed Wt (coalesced uint4/lane, L2-hot). fp32 MFMA accumulators.
// C/D layout (m89-verified): col = lane&15, row = (lane>>4)*4 + reg.

template <int K, int M, bool ABF16>
__global__ __launch_bounds__(256) void k_gemm(const void* __restrict__ Xv,
                                              const uint4* __restrict__ Wt,
                                              const float* __restrict__ dinv,
                                              unsigned short* __restrict__ Y,
                                              int N) {
  constexpr int KB = K / 32;   // mfma k-steps
  constexpr int CT = M / 16;   // col tiles
  constexpr int GR = K / 8;    // 16B granules per row
  __shared__ unsigned short lds[64 * 128];   // 64 rows x 256B (padded)
  const int tid  = threadIdx.x;
  const int base = blockIdx.x * 64;

  // ---- stage 64 rows as bf16 granules, swizzled ----
  for (int idx = tid; idx < 64 * GR; idx += 256) {
    int row = idx / GR;
    int g   = idx - row * GR;
    int srow = min(base + row, N - 1);
    uint4 pk;
    if (ABF16) {
      pk = *(const uint4*)((const unsigned short*)Xv + (size_t)srow * K + g * 8);
    } else {
      const float* xp = (const float*)Xv + (size_t)srow * K + g * 8;
      float4 v0 = *(const float4*)xp;
      float4 v1 = *(const float4*)(xp + 4);
      pk.x = (unsigned)f2bf(v0.x) | ((unsigned)f2bf(v0.y) << 16);
      pk.y = (unsigned)f2bf(v0.z) | ((unsigned)f2bf(v0.w) << 16);
      pk.z = (unsigned)f2bf(v1.x) | ((unsigned)f2bf(v1.y) << 16);
      pk.w = (unsigned)f2bf(v1.z) | ((unsigned)f2bf(v1.w) << 16);
    }
    int gs = g ^ (row & 7);
    *(uint4*)(&lds[row * 128 + gs * 8]) = pk;
  }
  __syncthreads();

  const int lane = tid & 63;
  const int wv   = tid >> 6;            // 0..3
  const int lrow = wv * 16 + (lane & 15);
  const int khi  = lane >> 4;           // 0..3

  f32x4 acc[CT];
#pragma unroll
  for (int c = 0; c < CT; ++c) acc[c] = (f32x4){0.f, 0.f, 0.f, 0.f};

  const bf16x8* Wb = (const bf16x8*)Wt;
#pragma unroll
  for (int kb = 0; kb < KB; ++kb) {
    int j  = khi + kb * 4;
    int js = j ^ (lrow & 7);
    bf16x8 a = *(const bf16x8*)(&lds[lrow * 128 + js * 8]);
#pragma unroll
    for (int c = 0; c < CT; ++c) {
      bf16x8 b = Wb[(c * KB + kb) * 64 + lane];
      acc[c] = __builtin_amdgcn_mfma_f32_16x16x32_bf16(a, b, acc[c], 0, 0, 0);
    }
  }

  // ---- epilogue: dinv scale + bf16 pack ----
  const int r0 = base + wv * 16 + khi * 4;
#pragma unroll
  for (int i = 0; i < 4; ++i) {
    int row = r0 + i;
    if (row < N) {
      float d = dinv[row];
      unsigned short* yp = Y + (size_t)row * M + (lane & 15);
#pragma unroll
      for (int c = 0; c < CT; ++c) {
        yp[c * 16] = f2bf(acc[c][i] * d);
      }
    }
  }
}

// ---------------- Aggregation (bf16 gathers) ----------------

__device__ __forceinline__ void bfacc(float* a, const uint4& v) {
  a[0] += bflo(v.x); a[1] += bfhi(v.x);
  a[2] += bflo(v.y); a[3] += bfhi(v.y);
  a[4] += bflo(v.z); a[5] += bfhi(v.z);
  a[6] += bflo(v.w); a[7] += bfhi(v.w);
}

template <int M, bool RELU, bool OBF16>
__global__ __launch_bounds__(256) void k_agg(const unsigned short* __restrict__ Hs,
                                             const int* __restrict__ csr,
                                             const int* __restrict__ rs,
                                             const int* __restrict__ cnt,
                                             const float* __restrict__ dinv,
                                             const float* __restrict__ bias,
                                             void* __restrict__ outv, int N) {
  constexpr int JC = M / 8;
  int gid = blockIdx.x * blockDim.x + threadIdx.x;
  int n = gid / JC;
  if (n >= N) return;
  int f8 = (gid - n * JC) * 8;
  float dn = dinv[n];
  float a[8] = {};
  {
    uint4 sv = *(const uint4*)(Hs + (size_t)n * M + f8);
    bfacc(a, sv);
  }
  int p = rs[n];
  int e = cnt[n];
  int i = 0;
  for (; i + 4 <= e; i += 4) {
    int s0 = csr[p + i];
    int s1 = csr[p + i + 1];
    int s2 = csr[p + i + 2];
    int s3 = csr[p + i + 3];
    uint4 g0 = *(const uint4*)(Hs + (size_t)s0 * M + f8);
    uint4 g1 = *(const uint4*)(Hs + (size_t)s1 * M + f8);
    uint4 g2 = *(const uint4*)(Hs + (size_t)s2 * M + f8);
    uint4 g3 = *(const uint4*)(Hs + (size_t)s3 * M + f8);
    bfacc(a, g0); bfacc(a, g1); bfacc(a, g2); bfacc(a, g3);
  }
  for (; i < e; ++i) {
    int s = csr[p + i];
    uint4 g = *(const uint4*)(Hs + (size_t)s * M + f8);
    bfacc(a, g);
  }
  float r[8];
#pragma unroll
  for (int q = 0; q < 8; ++q) {
    r[q] = fmaf(dn, a[q], bias[f8 + q]);
    if (RELU) r[q] = fmaxf(r[q], 0.0f);
  }
  if (OBF16) {
    uint4 pk;
    pk.x = (unsigned)f2bf(r[0]) | ((unsigned)f2bf(r[1]) << 16);
    pk.y = (unsigned)f2bf(r[2]) | ((unsigned)f2bf(r[3]) << 16);
    pk.z = (unsigned)f2bf(r[4]) | ((unsigned)f2bf(r[5]) << 16);
    pk.w = (unsigned)f2bf(r[6]) | ((unsigned)f2bf(r[7]) << 16);
    *(uint4*)((unsigned short*)outv + (size_t)n * M + f8) = pk;
  } else {
    float* op = (float*)outv + (size_t)n * M + f8;
    *(float4*)(op)     = make_float4(r[0], r[1], r[2], r[3]);
    *(float4*)(op + 4) = make_float4(r[4], r[5], r[6], r[7]);
  }
}

// ---------------- launch ----------------

extern "C" void kernel_launch(void* const* d_in, const int* in_sizes, int n_in,
                              void* d_out, int out_size, void* d_ws, size_t ws_size,
                              hipStream_t stream) {
  const float* x  = (const float*)d_in[0];
  const int*   ei = (const int*)d_in[1];
  const float* W1 = (const float*)d_in[2];
  const float* b1 = (const float*)d_in[3];
  const float* W2 = (const float*)d_in[4];
  const float* b2 = (const float*)d_in[5];
  float* out = (float*)d_out;

  const int N = in_sizes[0] / IN_C;     // 50000
  const int E = in_sizes[1] / 2;        // 800000
  const int* src = ei;
  const int* dst = ei + E;

  char* ws = (char*)d_ws;
  size_t off = 0;
  auto alloc = [&](size_t bytes) -> void* {
    void* p = ws + off;
    off = (off + bytes + 255) & ~(size_t)255;
    return p;
  };
  int*   cnt    = (int*)alloc((size_t)N * 4);
  int*   rs     = (int*)alloc((size_t)N * 4);
  float* dinv   = (float*)alloc((size_t)N * 4);
  int*   bsum   = (int*)alloc(256 * 4);
  int*   boff   = (int*)alloc(256 * 4);
  int*   junk   = (int*)alloc(256 * 4);
  int*   perm   = (int*)alloc((size_t)E * 4);
  int*   csr    = (int*)alloc((size_t)E * 4);
  unsigned short* hbf = (unsigned short*)alloc((size_t)N * HID * 2); // gemm outs
  unsigned short* hb2 = (unsigned short*)alloc((size_t)N * HID * 2); // agg1 out bf16
  constexpr int T1 = (HID / 16) * (IN_C / 32) * 64;   // 1536
  constexpr int T2 = (OUT_C / 16) * (HID / 32) * 64;  // 576
  uint4* Wt1 = (uint4*)alloc((size_t)T1 * 16);
  uint4* Wt2 = (uint4*)alloc((size_t)T2 * 16);

  const int nbN = (N + 255) / 256;
  const int nbE = (E + 255) / 256;
  const int P   = (N + NPART - 1) / NPART;

  k_zero<<<nbN, 256, 0, stream>>>(cnt, N);
  k_wprep<<<(T1 + T2 + 255) / 256, 256, 0, stream>>>(W1, Wt1, T1, W2, Wt2, T2);
  k_count<<<nbE, 256, 0, stream>>>(dst, cnt, perm, E);
  k_scan_block<<<nbN, 256, 0, stream>>>(cnt, rs, bsum, N);
  k_scan_block<<<1, 256, 0, stream>>>(bsum, boff, junk, nbN);
  k_finish<<<nbN, 256, 0, stream>>>(rs, boff, cnt, dinv, N);
  dim3 fg(NPART, (E + CHUNK - 1) / CHUNK);
  k_fill_part<<<fg, 256, 0, stream>>>(src, dst, perm, rs, csr, E, P);

  const int rowBlocks = (N + 63) / 64;   // 782

  // layer 1: hbf = bf16(dinv*(x@W1)); hb2 = bf16(relu(dinv*agg(hbf)+b1))
  {
    k_gemm<IN_C, HID, false><<<rowBlocks, 256, 0, stream>>>(x, Wt1, dinv, hbf, N);
    int t = N * (HID / 8);
    k_agg<HID, true, true><<<(t + 255) / 256, 256, 0, stream>>>(hbf, csr, rs, cnt, dinv, b1, hb2, N);
  }
  // layer 2: hbf = bf16(dinv*(hb2@W2)); out = dinv*agg(hbf) + b2
  {
    k_gemm<HID, OUT_C, true><<<rowBlocks, 256, 0, stream>>>(hb2, Wt2, dinv, hbf, N);
    int t = N * (OUT_C / 8);
    k_agg<OUT_C, false, false><<<(t + 255) / 256, 256, 0, stream>>>(hbf, csr, rs, cnt, dinv, b2, out, N);
  }
}